// Round 6
// baseline (561.331 us; speedup 1.0000x reference)
//
#include <hip/hip_runtime.h>
#include <hip/hip_bf16.h>
#include <cstddef>

#define N_NODES 20000
#define N_EDGES 320000
#define XDIM 128
#define H 256
#define LAYERS 4
#define G_GRAPHS 128
#define C_OUT 10
#define EPS_BN 1e-5f
#define NSLOT 64          // stats partial slots
#define WPN 8             // nodes per wave in agg

typedef __attribute__((ext_vector_type(8))) short short8;
typedef __attribute__((ext_vector_type(4))) float f32x4;

// ---------------- degree histogram (by dst) ----------------
__global__ void hist_kernel(const int* __restrict__ dst, int* __restrict__ cnt, int E) {
    int e = blockIdx.x * blockDim.x + threadIdx.x;
    if (e < E) atomicAdd(&cnt[dst[e]], 1);
}

// ---------------- exclusive scan of cnt -> rowstart[N+1], fused dinv ----------------
__global__ void scan_kernel(const int* __restrict__ cnt, int* __restrict__ rowstart,
                            float* __restrict__ dinv, int N) {
    __shared__ int partial[1024];
    int tid = threadIdx.x;
    int chunk = (N + 1023) / 1024;
    int start = tid * chunk;
    int lsum = 0;
    for (int i = 0; i < chunk; ++i) {
        int idx = start + i;
        if (idx < N) {
            int c = cnt[idx];
            dinv[idx] = 1.0f / sqrtf((float)c + 1.0f);
            lsum += c;
        }
    }
    partial[tid] = lsum;
    __syncthreads();
    for (int off = 1; off < 1024; off <<= 1) {
        int v = (tid >= off) ? partial[tid - off] : 0;
        __syncthreads();
        partial[tid] += v;
        __syncthreads();
    }
    int run = (tid == 0) ? 0 : partial[tid - 1];
    for (int i = 0; i < chunk; ++i) {
        int idx = start + i;
        if (idx < N) { rowstart[idx] = run; run += cnt[idx]; }
    }
    if (tid == 1023) rowstart[N] = partial[1023];
}

// ---------------- CSR fill ----------------
__global__ void fill_kernel(const int* __restrict__ src, const int* __restrict__ dst,
                            const int* __restrict__ rowstart, int* __restrict__ cursor,
                            const float* __restrict__ dinv,
                            int* __restrict__ csr_src, float* __restrict__ csr_w, int E) {
    int e = blockIdx.x * blockDim.x + threadIdx.x;
    if (e < E) {
        int s = src[e], d = dst[e];
        int pos = rowstart[d] + atomicAdd(&cursor[d], 1);
        csr_src[pos] = s;
        csr_w[pos] = dinv[s] * dinv[d];
    }
}

// ---------------- fp32 -> bf16 cast ----------------
__global__ void cast_bf16_kernel(const float* __restrict__ in, __hip_bfloat16* __restrict__ out, int n) {
    int i = blockIdx.x * blockDim.x + threadIdx.x;
    if (i < n) out[i] = __float2bfloat16(in[i]);
}

// ---------------- transpose+cast ----------------
__global__ void tcast_kernel(const float* __restrict__ in, __hip_bfloat16* __restrict__ out,
                             int R, int C, int layers) {
    int i = blockIdx.x * blockDim.x + threadIdx.x;
    int per = R * C;
    if (i >= per * layers) return;
    int l = i / per, rem = i - l * per;
    int r = rem / C, c = rem - r * C;
    out[(size_t)l * per + (size_t)c * R + r] = __float2bfloat16(in[i]);
}

// ---------------- bf16 MFMA GEMM (64x128 tile, 4 waves of 32x64, 16x16x32) ----------
// 64-row tiles double the block count vs 128x128 (626 blocks @ M=20000, Nn=256)
// to kill the 1.2-blocks/CU tail.
template <int K>
__global__ __launch_bounds__(256) void gemm_bf16_kernel(
    const __hip_bfloat16* __restrict__ A,   // [M,K] row-major
    const __hip_bfloat16* __restrict__ BT,  // [Nn,K] row-major (B transposed)
    const float* __restrict__ bias,         // [Nn] or nullptr
    __hip_bfloat16* __restrict__ Cbf,       // [M,Nn]
    int M, int Nn) {
    __shared__ short As[64 * 32];   // 4 KB
    __shared__ short Bs[128 * 32];  // 8 KB
    const short* Ash = (const short*)A;
    const short* Bsh = (const short*)BT;
    int tid = threadIdx.x;
    int lane = tid & 63;
    int wave = tid >> 6;
    int quad = lane >> 4;
    int lr = lane & 15;
    int wm = (wave & 1) * 32;
    int wn = (wave >> 1) * 64;
    int Mblk = blockIdx.x * 64;
    int Nblk = blockIdx.y * 128;

    f32x4 acc[2][4];
#pragma unroll
    for (int i = 0; i < 2; ++i)
#pragma unroll
        for (int j = 0; j < 4; ++j) acc[i][j] = (f32x4){0.f, 0.f, 0.f, 0.f};

    for (int k0 = 0; k0 < K; k0 += 32) {
        // A tile: 64 rows x 32 k = 4 KB = 256 x 16B, one pass
        {
            int row = tid >> 2;
            int qs = tid & 3;
            int qg = qs ^ ((row >> 1) & 3);
            int arow = Mblk + row; if (arow >= M) arow = M - 1;
            *(float4*)&As[row * 32 + qs * 8] =
                *(const float4*)(Ash + (size_t)arow * K + k0 + qg * 8);
        }
        // B tile: 128 rows x 32 k = 8 KB = 512 x 16B, two passes
#pragma unroll
        for (int i = 0; i < 2; ++i) {
            int s = i * 256 + tid;
            int row = s >> 2;
            int qs = s & 3;
            int qg = qs ^ ((row >> 1) & 3);
            int brow = Nblk + row;
            *(float4*)&Bs[row * 32 + qs * 8] =
                *(const float4*)(Bsh + (size_t)brow * K + k0 + qg * 8);
        }
        __syncthreads();
        short8 af[2], bfr[4];
#pragma unroll
        for (int mi = 0; mi < 2; ++mi) {
            int r = wm + mi * 16 + lr;
            af[mi] = *(const short8*)&As[r * 32 + (quad ^ ((r >> 1) & 3)) * 8];
        }
#pragma unroll
        for (int ni = 0; ni < 4; ++ni) {
            int r = wn + ni * 16 + lr;
            bfr[ni] = *(const short8*)&Bs[r * 32 + (quad ^ ((r >> 1) & 3)) * 8];
        }
#pragma unroll
        for (int mi = 0; mi < 2; ++mi)
#pragma unroll
            for (int ni = 0; ni < 4; ++ni)
                acc[mi][ni] = __builtin_amdgcn_mfma_f32_16x16x32_bf16(af[mi], bfr[ni], acc[mi][ni], 0, 0, 0);
        __syncthreads();
    }
#pragma unroll
    for (int mi = 0; mi < 2; ++mi) {
#pragma unroll
        for (int r = 0; r < 4; ++r) {
            int m = Mblk + wm + mi * 16 + quad * 4 + r;
            if (m < M) {
#pragma unroll
                for (int ni = 0; ni < 4; ++ni) {
                    int n = Nblk + wn + ni * 16 + lr;
                    float v = acc[mi][ni][r];
                    if (bias) v += bias[n];
                    Cbf[(size_t)m * Nn + n] = __float2bfloat16(v);
                }
            }
        }
    }
}

// ---------------- aggregation + fused BN-stats, wave-per-node -----------------
// One wave gathers a FULL 512B row per load (8B/lane = 4 channels). Wave owns
// WPN consecutive nodes; stats accumulate in registers across those nodes and
// flush with ONE atomicAdd set per wave (1.28M atomics total vs 10.2M before).
__global__ __launch_bounds__(256) void agg_kernel(const __hip_bfloat16* __restrict__ t,
                           const int* __restrict__ rowstart,
                           const int* __restrict__ csr_src,
                           const float* __restrict__ csr_w,
                           const float* __restrict__ dinv,
                           const float* __restrict__ convB,
                           float* __restrict__ out,
                           float* __restrict__ spart,  // [NSLOT][2*H]
                           int N) {
    int wave = threadIdx.x >> 6;
    int lane = threadIdx.x & 63;
    int wid = blockIdx.x * 4 + wave;
    int c0 = lane * 4;
    const ushort* tp = (const ushort*)t;
    float b0 = convB[c0], b1 = convB[c0 + 1], b2 = convB[c0 + 2], b3 = convB[c0 + 3];
    float sv0 = 0.f, sv1 = 0.f, sv2 = 0.f, sv3 = 0.f;
    float sq0 = 0.f, sq1 = 0.f, sq2 = 0.f, sq3 = 0.f;
#pragma unroll 1
    for (int it = 0; it < WPN; ++it) {
        int n = wid * WPN + it;   // grid sized so n < N always
        int s = rowstart[n], e = rowstart[n + 1];
        float a0 = 0.f, a1 = 0.f, a2 = 0.f, a3 = 0.f;
        int j = s;
        for (; j + 3 < e; j += 4) {
            int i0 = csr_src[j], i1 = csr_src[j + 1], i2 = csr_src[j + 2], i3 = csr_src[j + 3];
            float w0 = csr_w[j], w1 = csr_w[j + 1], w2 = csr_w[j + 2], w3 = csr_w[j + 3];
            uint2 v0 = *(const uint2*)(tp + (size_t)i0 * H + c0);
            uint2 v1 = *(const uint2*)(tp + (size_t)i1 * H + c0);
            uint2 v2 = *(const uint2*)(tp + (size_t)i2 * H + c0);
            uint2 v3 = *(const uint2*)(tp + (size_t)i3 * H + c0);
            a0 += __uint_as_float(v0.x << 16) * w0;
            a1 += __uint_as_float(v0.x & 0xffff0000u) * w0;
            a2 += __uint_as_float(v0.y << 16) * w0;
            a3 += __uint_as_float(v0.y & 0xffff0000u) * w0;
            a0 += __uint_as_float(v1.x << 16) * w1;
            a1 += __uint_as_float(v1.x & 0xffff0000u) * w1;
            a2 += __uint_as_float(v1.y << 16) * w1;
            a3 += __uint_as_float(v1.y & 0xffff0000u) * w1;
            a0 += __uint_as_float(v2.x << 16) * w2;
            a1 += __uint_as_float(v2.x & 0xffff0000u) * w2;
            a2 += __uint_as_float(v2.y << 16) * w2;
            a3 += __uint_as_float(v2.y & 0xffff0000u) * w2;
            a0 += __uint_as_float(v3.x << 16) * w3;
            a1 += __uint_as_float(v3.x & 0xffff0000u) * w3;
            a2 += __uint_as_float(v3.y << 16) * w3;
            a3 += __uint_as_float(v3.y & 0xffff0000u) * w3;
        }
        for (; j < e; ++j) {
            int i0 = csr_src[j];
            float w0 = csr_w[j];
            uint2 v0 = *(const uint2*)(tp + (size_t)i0 * H + c0);
            a0 += __uint_as_float(v0.x << 16) * w0;
            a1 += __uint_as_float(v0.x & 0xffff0000u) * w0;
            a2 += __uint_as_float(v0.y << 16) * w0;
            a3 += __uint_as_float(v0.y & 0xffff0000u) * w0;
        }
        float dn = dinv[n];
        float ws = dn * dn;
        uint2 vs = *(const uint2*)(tp + (size_t)n * H + c0);
        a0 += __uint_as_float(vs.x << 16) * ws + b0;
        a1 += __uint_as_float(vs.x & 0xffff0000u) * ws + b1;
        a2 += __uint_as_float(vs.y << 16) * ws + b2;
        a3 += __uint_as_float(vs.y & 0xffff0000u) * ws + b3;
        float4 o = make_float4(a0, a1, a2, a3);
        *(float4*)(out + (size_t)n * H + c0) = o;
        sv0 += a0; sq0 += a0 * a0;
        sv1 += a1; sq1 += a1 * a1;
        sv2 += a2; sq2 += a2 * a2;
        sv3 += a3; sq3 += a3 * a3;
    }
    float* sp = spart + (size_t)(wid & (NSLOT - 1)) * (2 * H);
    atomicAdd(&sp[c0], sv0);
    atomicAdd(&sp[c0 + 1], sv1);
    atomicAdd(&sp[c0 + 2], sv2);
    atomicAdd(&sp[c0 + 3], sv3);
    atomicAdd(&sp[H + c0], sq0);
    atomicAdd(&sp[H + c0 + 1], sq1);
    atomicAdd(&sp[H + c0 + 2], sq2);
    atomicAdd(&sp[H + c0 + 3], sq3);
}

// ---------------- reduce stats partials: [NSLOT][2H] -> [2H] ----------------
__global__ void reduce_stats_kernel(const float* __restrict__ spart, float* __restrict__ stats) {
    int c = blockIdx.x * 256 + threadIdx.x;  // 0..511
    float s = 0.f;
#pragma unroll 8
    for (int i = 0; i < NSLOT; ++i) s += spart[(size_t)i * (2 * H) + c];
    stats[c] = s;
}

// ---------------- BN (batch stats) + ReLU -> bf16 ----------------
__global__ void bnrelu_kernel(const float* __restrict__ t, const float* __restrict__ stats,
                              const float* __restrict__ gamma, const float* __restrict__ beta,
                              __hip_bfloat16* __restrict__ out, int N) {
    int c = threadIdx.x;  // H
    float invN = 1.0f / (float)N;
    float mean = stats[c] * invN;
    float var = stats[H + c] * invN - mean * mean;
    float sc = gamma[c] / sqrtf(var + EPS_BN);
    float sh = beta[c] - mean * sc;
    for (int r = blockIdx.x; r < N; r += gridDim.x) {
        float v = t[(size_t)r * H + c];
        out[(size_t)r * H + c] = __float2bfloat16(fmaxf(v * sc + sh, 0.f));
    }
}

// ---------------- global mean pool (batch sorted), full-row-per-wave ----------------
__global__ __launch_bounds__(256) void pool_kernel(const __hip_bfloat16* __restrict__ h,
                            const int* __restrict__ batch,
                            float* __restrict__ g, int N) {
    __shared__ float4 red[4][64];
    int gid = blockIdx.x;
    int lo = 0, hi = N;
    while (lo < hi) { int mid = (lo + hi) >> 1; if (batch[mid] < gid) lo = mid + 1; else hi = mid; }
    int s = lo;
    lo = s; hi = N;
    while (lo < hi) { int mid = (lo + hi) >> 1; if (batch[mid] < gid + 1) lo = mid + 1; else hi = mid; }
    int e = lo;
    int wave = threadIdx.x >> 6;
    int lane = threadIdx.x & 63;
    const ushort* hp = (const ushort*)h;
    float a0 = 0.f, a1 = 0.f, a2 = 0.f, a3 = 0.f;
    for (int r = s + wave; r < e; r += 4) {
        uint2 v = *(const uint2*)(hp + (size_t)r * H + lane * 4);
        a0 += __uint_as_float(v.x << 16);
        a1 += __uint_as_float(v.x & 0xffff0000u);
        a2 += __uint_as_float(v.y << 16);
        a3 += __uint_as_float(v.y & 0xffff0000u);
    }
    red[wave][lane] = make_float4(a0, a1, a2, a3);
    __syncthreads();
    int c = threadIdx.x;
    const float* rf = (const float*)red;
    float sum = rf[c] + rf[256 + c] + rf[512 + c] + rf[768 + c];
    g[(size_t)gid * H + c] = sum / fmaxf((float)(e - s), 1.0f);
}

// ---------------- FC with compile-time K/NN ----------------
template <int K, int NN>
__global__ __launch_bounds__(256) void fc_lds_kernel(const float* __restrict__ in,
                                                     const float* __restrict__ W,
                                                     const float* __restrict__ b,
                                                     float* __restrict__ out) {
    __shared__ float row[K];
    int g = blockIdx.x;
    for (int k = threadIdx.x; k < K; k += 256) row[k] = in[(size_t)g * K + k];
    __syncthreads();
    int hc = threadIdx.x;
    if (hc < NN) {
        float acc = b[hc];
#pragma unroll
        for (int k = 0; k < K; ++k) acc += row[k] * W[k * NN + hc];
        out[(size_t)g * NN + hc] = acc;
    }
}

// ---------------- final FC ----------------
__global__ void fc_out_kernel(const float* __restrict__ in, const float* __restrict__ W,
                              const float* __restrict__ b, float* __restrict__ out) {
    int t = blockIdx.x * blockDim.x + threadIdx.x;
    if (t >= G_GRAPHS * C_OUT) return;
    int g = t / C_OUT, c = t % C_OUT;
    float acc = b[c];
#pragma unroll 16
    for (int k = 0; k < H; ++k) acc += in[(size_t)g * H + k] * W[k * C_OUT + c];
    out[t] = acc;
}

// ---------------- BN over small [G,H] ----------------
__global__ void bn_head_kernel(const float* __restrict__ in, const float* __restrict__ gamma,
                               const float* __restrict__ beta, float* __restrict__ out,
                               int Grows, int relu) {
    int c = blockIdx.x;
    int r = threadIdx.x;
    __shared__ float red[G_GRAPHS];
    float v = in[r * H + c];
    red[r] = v;
    __syncthreads();
    for (int off = G_GRAPHS / 2; off > 0; off >>= 1) {
        if (r < off) red[r] += red[r + off];
        __syncthreads();
    }
    float mean = red[0] / (float)Grows;
    __syncthreads();
    float d = v - mean;
    red[r] = d * d;
    __syncthreads();
    for (int off = G_GRAPHS / 2; off > 0; off >>= 1) {
        if (r < off) red[r] += red[r + off];
        __syncthreads();
    }
    float var = red[0] / (float)Grows;
    float y = gamma[c] * d / sqrtf(var + EPS_BN) + beta[c];
    if (relu) y = fmaxf(y, 0.f);
    out[r * H + c] = y;
}

extern "C" void kernel_launch(void* const* d_in, const int* in_sizes, int n_in,
                              void* d_out, int out_size, void* d_ws, size_t ws_size,
                              hipStream_t stream) {
    const float* x     = (const float*)d_in[0];
    const int*   edge  = (const int*)d_in[1];
    const int*   batch = (const int*)d_in[2];
    const float* encW  = (const float*)d_in[3];
    const float* encB  = (const float*)d_in[4];
    const float* convW = (const float*)d_in[5];
    const float* convB = (const float*)d_in[6];
    const float* bnG   = (const float*)d_in[7];
    const float* bnB   = (const float*)d_in[8];
    const float* fcW1  = (const float*)d_in[9];
    const float* fcB1  = (const float*)d_in[10];
    const float* fcG1  = (const float*)d_in[11];
    const float* fcBe1 = (const float*)d_in[12];
    const float* fcW2  = (const float*)d_in[13];
    const float* fcB2  = (const float*)d_in[14];
    const float* fcG2  = (const float*)d_in[15];
    const float* fcBe2 = (const float*)d_in[16];
    const float* fcW3  = (const float*)d_in[17];
    const float* fcB3  = (const float*)d_in[18];
    float* out = (float*)d_out;

    const int* srcIdx = edge;
    const int* dstIdx = edge + N_EDGES;

    char* base = (char*)d_ws;
    size_t off = 0;
    auto alloc = [&](size_t bytes) -> void* {
        void* p = base + off;
        off = (off + bytes + 255) & ~(size_t)255;
        return p;
    };
    int*   cnt      = (int*)alloc(N_NODES * 4);
    int*   cursor   = (int*)alloc(N_NODES * 4);
    int*   rowstart = (int*)alloc((N_NODES + 1) * 4);
    float* dinv     = (float*)alloc(N_NODES * 4);
    int*   csr_src  = (int*)alloc(N_EDGES * 4);
    float* csr_w    = (float*)alloc(N_EDGES * 4);
    float* bnstats  = (float*)alloc(LAYERS * 2 * H * 4);
    float* spart    = (float*)alloc((size_t)LAYERS * NSLOT * 2 * H * 4);
    __hip_bfloat16* xbf    = (__hip_bfloat16*)alloc((size_t)N_NODES * XDIM * 2);
    __hip_bfloat16* encWT  = (__hip_bfloat16*)alloc((size_t)H * XDIM * 2);
    __hip_bfloat16* convWT = (__hip_bfloat16*)alloc((size_t)LAYERS * H * H * 2);
    __hip_bfloat16* hbf    = (__hip_bfloat16*)alloc((size_t)N_NODES * H * 2);
    __hip_bfloat16* tbf    = (__hip_bfloat16*)alloc((size_t)N_NODES * H * 2);
    float* t2buf = (float*)alloc((size_t)N_NODES * H * 4);
    float* gpool = (float*)alloc(G_GRAPHS * H * 4);
    float* m1    = (float*)alloc(G_GRAPHS * H * 4);
    float* m2    = (float*)alloc(G_GRAPHS * H * 4);

    hipMemsetAsync(cnt, 0, N_NODES * 4, stream);
    hipMemsetAsync(cursor, 0, N_NODES * 4, stream);
    hipMemsetAsync(spart, 0, (size_t)LAYERS * NSLOT * 2 * H * 4, stream);

    // CSR build
    hist_kernel<<<(N_EDGES + 255) / 256, 256, 0, stream>>>(dstIdx, cnt, N_EDGES);
    scan_kernel<<<1, 1024, 0, stream>>>(cnt, rowstart, dinv, N_NODES);
    fill_kernel<<<(N_EDGES + 255) / 256, 256, 0, stream>>>(srcIdx, dstIdx, rowstart, cursor,
                                                           dinv, csr_src, csr_w, N_EDGES);

    // casts
    cast_bf16_kernel<<<(N_NODES * XDIM + 255) / 256, 256, 0, stream>>>(x, xbf, N_NODES * XDIM);
    tcast_kernel<<<(XDIM * H + 255) / 256, 256, 0, stream>>>(encW, encWT, XDIM, H, 1);
    tcast_kernel<<<(LAYERS * H * H + 255) / 256, 256, 0, stream>>>(convW, convWT, H, H, LAYERS);

    // encoder
    dim3 gridG((N_NODES + 63) / 64, H / 128);
    gemm_bf16_kernel<XDIM><<<gridG, 256, 0, stream>>>(xbf, encWT, encB, hbf, N_NODES, H);

    // conv layers
    int aggBlocks = N_NODES / (4 * WPN);   // 625, exact
    for (int l = 0; l < LAYERS; ++l) {
        float* spartL = spart + (size_t)l * NSLOT * 2 * H;
        gemm_bf16_kernel<H><<<gridG, 256, 0, stream>>>(hbf, convWT + (size_t)l * H * H, nullptr,
                                                       tbf, N_NODES, H);
        agg_kernel<<<aggBlocks, 256, 0, stream>>>(tbf, rowstart, csr_src, csr_w, dinv,
                                                  convB + l * H, t2buf, spartL, N_NODES);
        reduce_stats_kernel<<<2, 256, 0, stream>>>(spartL, bnstats + l * 2 * H);
        bnrelu_kernel<<<512, H, 0, stream>>>(t2buf, bnstats + l * 2 * H,
                                             bnG + l * H, bnB + l * H, hbf, N_NODES);
    }

    // pool
    pool_kernel<<<G_GRAPHS, 256, 0, stream>>>(hbf, batch, gpool, N_NODES);

    // head
    fc_lds_kernel<H, H><<<G_GRAPHS, 256, 0, stream>>>(gpool, fcW1, fcB1, m1);
    bn_head_kernel<<<H, G_GRAPHS, 0, stream>>>(m1, fcG1, fcBe1, m1, G_GRAPHS, 1);
    fc_lds_kernel<H, H><<<G_GRAPHS, 256, 0, stream>>>(m1, fcW2, fcB2, m2);
    bn_head_kernel<<<H, G_GRAPHS, 0, stream>>>(m2, fcG2, fcBe2, m2, G_GRAPHS, 0);
    fc_out_kernel<<<(G_GRAPHS * C_OUT + 255) / 256, 256, 0, stream>>>(m2, fcW3, fcB3, out);
}

// Round 7
// 493.939 us; speedup vs baseline: 1.1364x; 1.1364x over previous
//
#include <hip/hip_runtime.h>
#include <hip/hip_bf16.h>
#include <cstddef>

#define N_NODES 20000
#define N_EDGES 320000
#define XDIM 128
#define H 256
#define LAYERS 4
#define G_GRAPHS 128
#define C_OUT 10
#define EPS_BN 1e-5f
#define NSLOT 64          // stats partial slots
#define NB 8              // nodes per block in agg

typedef __attribute__((ext_vector_type(8))) short short8;
typedef __attribute__((ext_vector_type(4))) float f32x4;

// ---------------- degree histogram (by dst) ----------------
__global__ void hist_kernel(const int* __restrict__ dst, int* __restrict__ cnt, int E) {
    int e = blockIdx.x * blockDim.x + threadIdx.x;
    if (e < E) atomicAdd(&cnt[dst[e]], 1);
}

// ---------------- exclusive scan of cnt -> rowstart[N+1], fused dinv ----------------
__global__ void scan_kernel(const int* __restrict__ cnt, int* __restrict__ rowstart,
                            float* __restrict__ dinv, int N) {
    __shared__ int partial[1024];
    int tid = threadIdx.x;
    int chunk = (N + 1023) / 1024;
    int start = tid * chunk;
    int lsum = 0;
    for (int i = 0; i < chunk; ++i) {
        int idx = start + i;
        if (idx < N) {
            int c = cnt[idx];
            dinv[idx] = 1.0f / sqrtf((float)c + 1.0f);
            lsum += c;
        }
    }
    partial[tid] = lsum;
    __syncthreads();
    for (int off = 1; off < 1024; off <<= 1) {
        int v = (tid >= off) ? partial[tid - off] : 0;
        __syncthreads();
        partial[tid] += v;
        __syncthreads();
    }
    int run = (tid == 0) ? 0 : partial[tid - 1];
    for (int i = 0; i < chunk; ++i) {
        int idx = start + i;
        if (idx < N) { rowstart[idx] = run; run += cnt[idx]; }
    }
    if (tid == 1023) rowstart[N] = partial[1023];
}

// ---------------- CSR fill ----------------
__global__ void fill_kernel(const int* __restrict__ src, const int* __restrict__ dst,
                            const int* __restrict__ rowstart, int* __restrict__ cursor,
                            const float* __restrict__ dinv,
                            int* __restrict__ csr_src, float* __restrict__ csr_w, int E) {
    int e = blockIdx.x * blockDim.x + threadIdx.x;
    if (e < E) {
        int s = src[e], d = dst[e];
        int pos = rowstart[d] + atomicAdd(&cursor[d], 1);
        csr_src[pos] = s;
        csr_w[pos] = dinv[s] * dinv[d];
    }
}

// ---------------- fp32 -> bf16 cast ----------------
__global__ void cast_bf16_kernel(const float* __restrict__ in, __hip_bfloat16* __restrict__ out, int n) {
    int i = blockIdx.x * blockDim.x + threadIdx.x;
    if (i < n) out[i] = __float2bfloat16(in[i]);
}

// ---------------- transpose+cast ----------------
__global__ void tcast_kernel(const float* __restrict__ in, __hip_bfloat16* __restrict__ out,
                             int R, int C, int layers) {
    int i = blockIdx.x * blockDim.x + threadIdx.x;
    int per = R * C;
    if (i >= per * layers) return;
    int l = i / per, rem = i - l * per;
    int r = rem / C, c = rem - r * C;
    out[(size_t)l * per + (size_t)c * R + r] = __float2bfloat16(in[i]);
}

// ---------------- bf16 MFMA GEMM (64x128 tile, 4 waves of 32x64, 16x16x32) ----------
template <int K>
__global__ __launch_bounds__(256) void gemm_bf16_kernel(
    const __hip_bfloat16* __restrict__ A,   // [M,K] row-major
    const __hip_bfloat16* __restrict__ BT,  // [Nn,K] row-major (B transposed)
    const float* __restrict__ bias,         // [Nn] or nullptr
    __hip_bfloat16* __restrict__ Cbf,       // [M,Nn]
    int M, int Nn) {
    __shared__ short As[64 * 32];   // 4 KB
    __shared__ short Bs[128 * 32];  // 8 KB
    const short* Ash = (const short*)A;
    const short* Bsh = (const short*)BT;
    int tid = threadIdx.x;
    int lane = tid & 63;
    int wave = tid >> 6;
    int quad = lane >> 4;
    int lr = lane & 15;
    int wm = (wave & 1) * 32;
    int wn = (wave >> 1) * 64;
    int Mblk = blockIdx.x * 64;
    int Nblk = blockIdx.y * 128;

    f32x4 acc[2][4];
#pragma unroll
    for (int i = 0; i < 2; ++i)
#pragma unroll
        for (int j = 0; j < 4; ++j) acc[i][j] = (f32x4){0.f, 0.f, 0.f, 0.f};

    for (int k0 = 0; k0 < K; k0 += 32) {
        {
            int row = tid >> 2;
            int qs = tid & 3;
            int qg = qs ^ ((row >> 1) & 3);
            int arow = Mblk + row; if (arow >= M) arow = M - 1;
            *(float4*)&As[row * 32 + qs * 8] =
                *(const float4*)(Ash + (size_t)arow * K + k0 + qg * 8);
        }
#pragma unroll
        for (int i = 0; i < 2; ++i) {
            int s = i * 256 + tid;
            int row = s >> 2;
            int qs = s & 3;
            int qg = qs ^ ((row >> 1) & 3);
            int brow = Nblk + row;
            *(float4*)&Bs[row * 32 + qs * 8] =
                *(const float4*)(Bsh + (size_t)brow * K + k0 + qg * 8);
        }
        __syncthreads();
        short8 af[2], bfr[4];
#pragma unroll
        for (int mi = 0; mi < 2; ++mi) {
            int r = wm + mi * 16 + lr;
            af[mi] = *(const short8*)&As[r * 32 + (quad ^ ((r >> 1) & 3)) * 8];
        }
#pragma unroll
        for (int ni = 0; ni < 4; ++ni) {
            int r = wn + ni * 16 + lr;
            bfr[ni] = *(const short8*)&Bs[r * 32 + (quad ^ ((r >> 1) & 3)) * 8];
        }
#pragma unroll
        for (int mi = 0; mi < 2; ++mi)
#pragma unroll
            for (int ni = 0; ni < 4; ++ni)
                acc[mi][ni] = __builtin_amdgcn_mfma_f32_16x16x32_bf16(af[mi], bfr[ni], acc[mi][ni], 0, 0, 0);
        __syncthreads();
    }
#pragma unroll
    for (int mi = 0; mi < 2; ++mi) {
#pragma unroll
        for (int r = 0; r < 4; ++r) {
            int m = Mblk + wm + mi * 16 + quad * 4 + r;
            if (m < M) {
#pragma unroll
                for (int ni = 0; ni < 4; ++ni) {
                    int n = Nblk + wn + ni * 16 + lr;
                    float v = acc[mi][ni][r];
                    if (bias) v += bias[n];
                    Cbf[(size_t)m * Nn + n] = __float2bfloat16(v);
                }
            }
        }
    }
}

// ---------------- aggregation + fused BN-stats, v3 -----------------
// Block = NB consecutive nodes, processed sequentially by all 4 waves.
// 8 edge-streams/block (half-wave each); a 32-lane half-wave gathers a FULL
// 512B row per uint4 load (16B/lane = 8 channels). 16 rows in flight per
// block x ~8 blocks/CU resident. Stats accumulate in registers across the
// NB nodes; ONE atomic flush per block (1.28M atomics total).
__global__ __launch_bounds__(256) void agg_kernel(const __hip_bfloat16* __restrict__ t,
                           const int* __restrict__ rowstart,
                           const int* __restrict__ csr_src,
                           const float* __restrict__ csr_w,
                           const float* __restrict__ dinv,
                           const float* __restrict__ convB,
                           float* __restrict__ out,
                           float* __restrict__ spart,  // [NSLOT][2*H]
                           int N) {
    __shared__ float red[4][256];  // 4 KB
    int tid = threadIdx.x;
    int wave = tid >> 6;
    int lane = tid & 63;
    int sub = lane >> 5;          // half-wave
    int hl = lane & 31;
    int stream = wave * 2 + sub;  // 0..7
    int c0 = hl * 8;              // gather channel base (8 channels/lane)
    const ushort* tp = (const ushort*)t;
    float sv = 0.f, sq = 0.f;
    int n0 = blockIdx.x * NB;
#pragma unroll 1
    for (int it = 0; it < NB; ++it) {
        int n = n0 + it;
        int s = rowstart[n], e = rowstart[n + 1];
        float a[8] = {};
#pragma unroll 1
        for (int j0 = s; j0 < e; j0 += 16) {
#pragma unroll
            for (int u = 0; u < 2; ++u) {
                int j = j0 + u * 8 + stream;
                int idx = n; float w = 0.f;
                if (j < e) { idx = csr_src[j]; w = csr_w[j]; }
                uint4 v = *(const uint4*)(tp + (size_t)idx * H + c0);
                a[0] += __uint_as_float(v.x << 16) * w;
                a[1] += __uint_as_float(v.x & 0xffff0000u) * w;
                a[2] += __uint_as_float(v.y << 16) * w;
                a[3] += __uint_as_float(v.y & 0xffff0000u) * w;
                a[4] += __uint_as_float(v.z << 16) * w;
                a[5] += __uint_as_float(v.z & 0xffff0000u) * w;
                a[6] += __uint_as_float(v.w << 16) * w;
                a[7] += __uint_as_float(v.w & 0xffff0000u) * w;
            }
        }
        // combine the two half-waves of each wave
#pragma unroll
        for (int k = 0; k < 8; ++k) a[k] += __shfl_xor(a[k], 32);
        if (sub == 0) {
            *(float4*)&red[wave][c0] = make_float4(a[0], a[1], a[2], a[3]);
            *(float4*)&red[wave][c0 + 4] = make_float4(a[4], a[5], a[6], a[7]);
        }
        __syncthreads();
        int c = tid;  // channel
        float val = red[0][c] + red[1][c] + red[2][c] + red[3][c];
        float dn = dinv[n];
        val += __bfloat162float(t[(size_t)n * H + c]) * (dn * dn) + convB[c];
        out[(size_t)n * H + c] = val;
        sv += val; sq += val * val;
        __syncthreads();
    }
    float* sp = spart + (size_t)(blockIdx.x & (NSLOT - 1)) * (2 * H);
    atomicAdd(&sp[tid], sv);
    atomicAdd(&sp[H + tid], sq);
}

// ---------------- reduce stats partials: [NSLOT][2H] -> [2H] ----------------
__global__ void reduce_stats_kernel(const float* __restrict__ spart, float* __restrict__ stats) {
    int c = blockIdx.x * 256 + threadIdx.x;  // 0..511
    float s = 0.f;
#pragma unroll 8
    for (int i = 0; i < NSLOT; ++i) s += spart[(size_t)i * (2 * H) + c];
    stats[c] = s;
}

// ---------------- BN (batch stats) + ReLU -> bf16 ----------------
__global__ void bnrelu_kernel(const float* __restrict__ t, const float* __restrict__ stats,
                              const float* __restrict__ gamma, const float* __restrict__ beta,
                              __hip_bfloat16* __restrict__ out, int N) {
    int c = threadIdx.x;  // H
    float invN = 1.0f / (float)N;
    float mean = stats[c] * invN;
    float var = stats[H + c] * invN - mean * mean;
    float sc = gamma[c] / sqrtf(var + EPS_BN);
    float sh = beta[c] - mean * sc;
    for (int r = blockIdx.x; r < N; r += gridDim.x) {
        float v = t[(size_t)r * H + c];
        out[(size_t)r * H + c] = __float2bfloat16(fmaxf(v * sc + sh, 0.f));
    }
}

// ---------------- global mean pool (batch sorted), full-row-per-wave ----------------
__global__ __launch_bounds__(256) void pool_kernel(const __hip_bfloat16* __restrict__ h,
                            const int* __restrict__ batch,
                            float* __restrict__ g, int N) {
    __shared__ float4 red[4][64];
    int gid = blockIdx.x;
    int lo = 0, hi = N;
    while (lo < hi) { int mid = (lo + hi) >> 1; if (batch[mid] < gid) lo = mid + 1; else hi = mid; }
    int s = lo;
    lo = s; hi = N;
    while (lo < hi) { int mid = (lo + hi) >> 1; if (batch[mid] < gid + 1) lo = mid + 1; else hi = mid; }
    int e = lo;
    int wave = threadIdx.x >> 6;
    int lane = threadIdx.x & 63;
    const ushort* hp = (const ushort*)h;
    float a0 = 0.f, a1 = 0.f, a2 = 0.f, a3 = 0.f;
    for (int r = s + wave; r < e; r += 4) {
        uint2 v = *(const uint2*)(hp + (size_t)r * H + lane * 4);
        a0 += __uint_as_float(v.x << 16);
        a1 += __uint_as_float(v.x & 0xffff0000u);
        a2 += __uint_as_float(v.y << 16);
        a3 += __uint_as_float(v.y & 0xffff0000u);
    }
    red[wave][lane] = make_float4(a0, a1, a2, a3);
    __syncthreads();
    int c = threadIdx.x;
    const float* rf = (const float*)red;
    float sum = rf[c] + rf[256 + c] + rf[512 + c] + rf[768 + c];
    g[(size_t)gid * H + c] = sum / fmaxf((float)(e - s), 1.0f);
}

// ---------------- FC with compile-time K/NN ----------------
template <int K, int NN>
__global__ __launch_bounds__(256) void fc_lds_kernel(const float* __restrict__ in,
                                                     const float* __restrict__ W,
                                                     const float* __restrict__ b,
                                                     float* __restrict__ out) {
    __shared__ float row[K];
    int g = blockIdx.x;
    for (int k = threadIdx.x; k < K; k += 256) row[k] = in[(size_t)g * K + k];
    __syncthreads();
    int hc = threadIdx.x;
    if (hc < NN) {
        float acc = b[hc];
#pragma unroll
        for (int k = 0; k < K; ++k) acc += row[k] * W[k * NN + hc];
        out[(size_t)g * NN + hc] = acc;
    }
}

// ---------------- final FC ----------------
__global__ void fc_out_kernel(const float* __restrict__ in, const float* __restrict__ W,
                              const float* __restrict__ b, float* __restrict__ out) {
    int t = blockIdx.x * blockDim.x + threadIdx.x;
    if (t >= G_GRAPHS * C_OUT) return;
    int g = t / C_OUT, c = t % C_OUT;
    float acc = b[c];
#pragma unroll 16
    for (int k = 0; k < H; ++k) acc += in[(size_t)g * H + k] * W[k * C_OUT + c];
    out[t] = acc;
}

// ---------------- BN over small [G,H] ----------------
__global__ void bn_head_kernel(const float* __restrict__ in, const float* __restrict__ gamma,
                               const float* __restrict__ beta, float* __restrict__ out,
                               int Grows, int relu) {
    int c = blockIdx.x;
    int r = threadIdx.x;
    __shared__ float red[G_GRAPHS];
    float v = in[r * H + c];
    red[r] = v;
    __syncthreads();
    for (int off = G_GRAPHS / 2; off > 0; off >>= 1) {
        if (r < off) red[r] += red[r + off];
        __syncthreads();
    }
    float mean = red[0] / (float)Grows;
    __syncthreads();
    float d = v - mean;
    red[r] = d * d;
    __syncthreads();
    for (int off = G_GRAPHS / 2; off > 0; off >>= 1) {
        if (r < off) red[r] += red[r + off];
        __syncthreads();
    }
    float var = red[0] / (float)Grows;
    float y = gamma[c] * d / sqrtf(var + EPS_BN) + beta[c];
    if (relu) y = fmaxf(y, 0.f);
    out[r * H + c] = y;
}

extern "C" void kernel_launch(void* const* d_in, const int* in_sizes, int n_in,
                              void* d_out, int out_size, void* d_ws, size_t ws_size,
                              hipStream_t stream) {
    const float* x     = (const float*)d_in[0];
    const int*   edge  = (const int*)d_in[1];
    const int*   batch = (const int*)d_in[2];
    const float* encW  = (const float*)d_in[3];
    const float* encB  = (const float*)d_in[4];
    const float* convW = (const float*)d_in[5];
    const float* convB = (const float*)d_in[6];
    const float* bnG   = (const float*)d_in[7];
    const float* bnB   = (const float*)d_in[8];
    const float* fcW1  = (const float*)d_in[9];
    const float* fcB1  = (const float*)d_in[10];
    const float* fcG1  = (const float*)d_in[11];
    const float* fcBe1 = (const float*)d_in[12];
    const float* fcW2  = (const float*)d_in[13];
    const float* fcB2  = (const float*)d_in[14];
    const float* fcG2  = (const float*)d_in[15];
    const float* fcBe2 = (const float*)d_in[16];
    const float* fcW3  = (const float*)d_in[17];
    const float* fcB3  = (const float*)d_in[18];
    float* out = (float*)d_out;

    const int* srcIdx = edge;
    const int* dstIdx = edge + N_EDGES;

    char* base = (char*)d_ws;
    size_t off = 0;
    auto alloc = [&](size_t bytes) -> void* {
        void* p = base + off;
        off = (off + bytes + 255) & ~(size_t)255;
        return p;
    };
    int*   cnt      = (int*)alloc(N_NODES * 4);
    int*   cursor   = (int*)alloc(N_NODES * 4);
    int*   rowstart = (int*)alloc((N_NODES + 1) * 4);
    float* dinv     = (float*)alloc(N_NODES * 4);
    int*   csr_src  = (int*)alloc(N_EDGES * 4);
    float* csr_w    = (float*)alloc(N_EDGES * 4);
    float* bnstats  = (float*)alloc(LAYERS * 2 * H * 4);
    float* spart    = (float*)alloc((size_t)LAYERS * NSLOT * 2 * H * 4);
    __hip_bfloat16* xbf    = (__hip_bfloat16*)alloc((size_t)N_NODES * XDIM * 2);
    __hip_bfloat16* encWT  = (__hip_bfloat16*)alloc((size_t)H * XDIM * 2);
    __hip_bfloat16* convWT = (__hip_bfloat16*)alloc((size_t)LAYERS * H * H * 2);
    __hip_bfloat16* hbf    = (__hip_bfloat16*)alloc((size_t)N_NODES * H * 2);
    __hip_bfloat16* tbf    = (__hip_bfloat16*)alloc((size_t)N_NODES * H * 2);
    float* t2buf = (float*)alloc((size_t)N_NODES * H * 4);
    float* gpool = (float*)alloc(G_GRAPHS * H * 4);
    float* m1    = (float*)alloc(G_GRAPHS * H * 4);
    float* m2    = (float*)alloc(G_GRAPHS * H * 4);

    hipMemsetAsync(cnt, 0, N_NODES * 4, stream);
    hipMemsetAsync(cursor, 0, N_NODES * 4, stream);
    hipMemsetAsync(spart, 0, (size_t)LAYERS * NSLOT * 2 * H * 4, stream);

    // CSR build
    hist_kernel<<<(N_EDGES + 255) / 256, 256, 0, stream>>>(dstIdx, cnt, N_EDGES);
    scan_kernel<<<1, 1024, 0, stream>>>(cnt, rowstart, dinv, N_NODES);
    fill_kernel<<<(N_EDGES + 255) / 256, 256, 0, stream>>>(srcIdx, dstIdx, rowstart, cursor,
                                                           dinv, csr_src, csr_w, N_EDGES);

    // casts
    cast_bf16_kernel<<<(N_NODES * XDIM + 255) / 256, 256, 0, stream>>>(x, xbf, N_NODES * XDIM);
    tcast_kernel<<<(XDIM * H + 255) / 256, 256, 0, stream>>>(encW, encWT, XDIM, H, 1);
    tcast_kernel<<<(LAYERS * H * H + 255) / 256, 256, 0, stream>>>(convW, convWT, H, H, LAYERS);

    // encoder
    dim3 gridG((N_NODES + 63) / 64, H / 128);
    gemm_bf16_kernel<XDIM><<<gridG, 256, 0, stream>>>(xbf, encWT, encB, hbf, N_NODES, H);

    // conv layers
    for (int l = 0; l < LAYERS; ++l) {
        float* spartL = spart + (size_t)l * NSLOT * 2 * H;
        gemm_bf16_kernel<H><<<gridG, 256, 0, stream>>>(hbf, convWT + (size_t)l * H * H, nullptr,
                                                       tbf, N_NODES, H);
        agg_kernel<<<N_NODES / NB, 256, 0, stream>>>(tbf, rowstart, csr_src, csr_w, dinv,
                                                     convB + l * H, t2buf, spartL, N_NODES);
        reduce_stats_kernel<<<2, 256, 0, stream>>>(spartL, bnstats + l * 2 * H);
        bnrelu_kernel<<<512, H, 0, stream>>>(t2buf, bnstats + l * 2 * H,
                                             bnG + l * H, bnB + l * H, hbf, N_NODES);
    }

    // pool
    pool_kernel<<<G_GRAPHS, 256, 0, stream>>>(hbf, batch, gpool, N_NODES);

    // head
    fc_lds_kernel<H, H><<<G_GRAPHS, 256, 0, stream>>>(gpool, fcW1, fcB1, m1);
    bn_head_kernel<<<H, G_GRAPHS, 0, stream>>>(m1, fcG1, fcBe1, m1, G_GRAPHS, 1);
    fc_lds_kernel<H, H><<<G_GRAPHS, 256, 0, stream>>>(m1, fcW2, fcB2, m2);
    bn_head_kernel<<<H, G_GRAPHS, 0, stream>>>(m2, fcG2, fcBe2, m2, G_GRAPHS, 0);
    fc_out_kernel<<<(G_GRAPHS * C_OUT + 255) / 256, 256, 0, stream>>>(m2, fcW3, fcB3, out);
}

// Round 8
// 453.420 us; speedup vs baseline: 1.2380x; 1.0894x over previous
//
#include <hip/hip_runtime.h>
#include <hip/hip_bf16.h>
#include <cstddef>

#define N_NODES 20000
#define N_EDGES 320000
#define XDIM 128
#define H 256
#define LAYERS 4
#define G_GRAPHS 128
#define C_OUT 10
#define EPS_BN 1e-5f
#define NSLOT 64          // stats partial slots
#define NB 8              // nodes per block in agg

typedef __attribute__((ext_vector_type(8))) short short8;
typedef __attribute__((ext_vector_type(4))) float f32x4;
typedef __attribute__((address_space(3))) unsigned int lds_u32;
typedef const __attribute__((address_space(1))) unsigned int glob_u32;

// ---------------- degree histogram (by dst) ----------------
__global__ void hist_kernel(const int* __restrict__ dst, int* __restrict__ cnt, int E) {
    int e = blockIdx.x * blockDim.x + threadIdx.x;
    if (e < E) atomicAdd(&cnt[dst[e]], 1);
}

// ---------------- exclusive scan of cnt -> rowstart[N+1], fused dinv ----------------
__global__ void scan_kernel(const int* __restrict__ cnt, int* __restrict__ rowstart,
                            float* __restrict__ dinv, int N) {
    __shared__ int partial[1024];
    int tid = threadIdx.x;
    int chunk = (N + 1023) / 1024;
    int start = tid * chunk;
    int lsum = 0;
    for (int i = 0; i < chunk; ++i) {
        int idx = start + i;
        if (idx < N) {
            int c = cnt[idx];
            dinv[idx] = 1.0f / sqrtf((float)c + 1.0f);
            lsum += c;
        }
    }
    partial[tid] = lsum;
    __syncthreads();
    for (int off = 1; off < 1024; off <<= 1) {
        int v = (tid >= off) ? partial[tid - off] : 0;
        __syncthreads();
        partial[tid] += v;
        __syncthreads();
    }
    int run = (tid == 0) ? 0 : partial[tid - 1];
    for (int i = 0; i < chunk; ++i) {
        int idx = start + i;
        if (idx < N) { rowstart[idx] = run; run += cnt[idx]; }
    }
    if (tid == 1023) rowstart[N] = partial[1023];
}

// ---------------- CSR fill ----------------
__global__ void fill_kernel(const int* __restrict__ src, const int* __restrict__ dst,
                            const int* __restrict__ rowstart, int* __restrict__ cursor,
                            const float* __restrict__ dinv,
                            int* __restrict__ csr_src, float* __restrict__ csr_w, int E) {
    int e = blockIdx.x * blockDim.x + threadIdx.x;
    if (e < E) {
        int s = src[e], d = dst[e];
        int pos = rowstart[d] + atomicAdd(&cursor[d], 1);
        csr_src[pos] = s;
        csr_w[pos] = dinv[s] * dinv[d];
    }
}

// ---------------- fp32 -> bf16 cast ----------------
__global__ void cast_bf16_kernel(const float* __restrict__ in, __hip_bfloat16* __restrict__ out, int n) {
    int i = blockIdx.x * blockDim.x + threadIdx.x;
    if (i < n) out[i] = __float2bfloat16(in[i]);
}

// ---------------- transpose+cast ----------------
__global__ void tcast_kernel(const float* __restrict__ in, __hip_bfloat16* __restrict__ out,
                             int R, int C, int layers) {
    int i = blockIdx.x * blockDim.x + threadIdx.x;
    int per = R * C;
    if (i >= per * layers) return;
    int l = i / per, rem = i - l * per;
    int r = rem / C, c = rem - r * C;
    out[(size_t)l * per + (size_t)c * R + r] = __float2bfloat16(in[i]);
}

__device__ __forceinline__ short bf16bits(float x) {
    __hip_bfloat16 b = __float2bfloat16(x);
    return *(short*)&b;
}

// ---------------- bf16 MFMA GEMM (64x128 tile, 4 waves of 32x64, 16x16x32) ----------
// B staged via async global_load_lds (16B). A: async when plain bf16 input;
// when FUSE_BN, A is fp32 agg output and BN+ReLU (sc/sh affine) is applied
// while staging (VALU path), matching the old bnrelu->bf16 rounding exactly.
template <int K, bool FUSE_BN>
__global__ __launch_bounds__(256) void gemm_bf16_kernel(
    const void* __restrict__ Ain,           // [M,K] bf16 (plain) or fp32 (FUSE_BN)
    const __hip_bfloat16* __restrict__ BT,  // [Nn,K] row-major (B transposed)
    const float* __restrict__ bias,         // [Nn] or nullptr
    const float* __restrict__ bnsc,         // [K] BN scale (FUSE_BN)
    const float* __restrict__ bnsh,         // [K] BN shift (FUSE_BN)
    __hip_bfloat16* __restrict__ Cbf,       // [M,Nn]
    int M, int Nn) {
    __shared__ short As[64 * 32];   // 4 KB
    __shared__ short Bs[128 * 32];  // 8 KB
    const short* Ash = (const short*)Ain;
    const float* Af = (const float*)Ain;
    const short* Bsh = (const short*)BT;
    int tid = threadIdx.x;
    int lane = tid & 63;
    int wave = tid >> 6;
    int quad = lane >> 4;
    int lr = lane & 15;
    int wm = (wave & 1) * 32;
    int wn = (wave >> 1) * 64;
    int Mblk = blockIdx.x * 64;
    int Nblk = blockIdx.y * 128;

    f32x4 acc[2][4];
#pragma unroll
    for (int i = 0; i < 2; ++i)
#pragma unroll
        for (int j = 0; j < 4; ++j) acc[i][j] = (f32x4){0.f, 0.f, 0.f, 0.f};

    // this thread's staging slot (constant over K)
    int srow = tid >> 2, sqs = tid & 3;
    int sqg = sqs ^ ((srow >> 1) & 3);
    int arow = Mblk + srow; if (arow >= M) arow = M - 1;
    int s1 = 256 + tid;
    int brow0 = Nblk + (tid >> 2);
    int qg0 = sqg;                          // same formula as A slot
    int brow1 = Nblk + (s1 >> 2);
    int qg1 = (s1 & 3) ^ (((s1 >> 2) >> 1) & 3);

    for (int k0 = 0; k0 < K; k0 += 32) {
        int kc = k0 + sqg * 8;
        // B staging: async 16B direct-to-LDS, both halves
        __builtin_amdgcn_global_load_lds((glob_u32*)(Bsh + (size_t)brow0 * K + k0 + qg0 * 8),
                                         (lds_u32*)Bs + wave * 256, 16, 0, 0);
        __builtin_amdgcn_global_load_lds((glob_u32*)(Bsh + (size_t)brow1 * K + k0 + qg1 * 8),
                                         (lds_u32*)Bs + 1024 + wave * 256, 16, 0, 0);
        if (FUSE_BN) {
            float4 v0 = *(const float4*)(Af + (size_t)arow * K + kc);
            float4 v1 = *(const float4*)(Af + (size_t)arow * K + kc + 4);
            float4 c0 = *(const float4*)(bnsc + kc);
            float4 c1 = *(const float4*)(bnsc + kc + 4);
            float4 h0 = *(const float4*)(bnsh + kc);
            float4 h1 = *(const float4*)(bnsh + kc + 4);
            short8 pk;
            pk[0] = bf16bits(fmaxf(v0.x * c0.x + h0.x, 0.f));
            pk[1] = bf16bits(fmaxf(v0.y * c0.y + h0.y, 0.f));
            pk[2] = bf16bits(fmaxf(v0.z * c0.z + h0.z, 0.f));
            pk[3] = bf16bits(fmaxf(v0.w * c0.w + h0.w, 0.f));
            pk[4] = bf16bits(fmaxf(v1.x * c1.x + h1.x, 0.f));
            pk[5] = bf16bits(fmaxf(v1.y * c1.y + h1.y, 0.f));
            pk[6] = bf16bits(fmaxf(v1.z * c1.z + h1.z, 0.f));
            pk[7] = bf16bits(fmaxf(v1.w * c1.w + h1.w, 0.f));
            *(short8*)&As[srow * 32 + sqs * 8] = pk;
        } else {
            __builtin_amdgcn_global_load_lds((glob_u32*)(Ash + (size_t)arow * K + kc),
                                             (lds_u32*)As + wave * 256, 16, 0, 0);
        }
        __syncthreads();
        short8 af[2], bfr[4];
#pragma unroll
        for (int mi = 0; mi < 2; ++mi) {
            int r = wm + mi * 16 + lr;
            af[mi] = *(const short8*)&As[r * 32 + (quad ^ ((r >> 1) & 3)) * 8];
        }
#pragma unroll
        for (int ni = 0; ni < 4; ++ni) {
            int r = wn + ni * 16 + lr;
            bfr[ni] = *(const short8*)&Bs[r * 32 + (quad ^ ((r >> 1) & 3)) * 8];
        }
#pragma unroll
        for (int mi = 0; mi < 2; ++mi)
#pragma unroll
            for (int ni = 0; ni < 4; ++ni)
                acc[mi][ni] = __builtin_amdgcn_mfma_f32_16x16x32_bf16(af[mi], bfr[ni], acc[mi][ni], 0, 0, 0);
        __syncthreads();
    }
#pragma unroll
    for (int mi = 0; mi < 2; ++mi) {
#pragma unroll
        for (int r = 0; r < 4; ++r) {
            int m = Mblk + wm + mi * 16 + quad * 4 + r;
            if (m < M) {
#pragma unroll
                for (int ni = 0; ni < 4; ++ni) {
                    int n = Nblk + wn + ni * 16 + lr;
                    float v = acc[mi][ni][r];
                    if (bias) v += bias[n];
                    Cbf[(size_t)m * Nn + n] = __float2bfloat16(v);
                }
            }
        }
    }
}

// ---------------- aggregation + fused BN-stats (R7 structure, unchanged) ----------
__global__ __launch_bounds__(256) void agg_kernel(const __hip_bfloat16* __restrict__ t,
                           const int* __restrict__ rowstart,
                           const int* __restrict__ csr_src,
                           const float* __restrict__ csr_w,
                           const float* __restrict__ dinv,
                           const float* __restrict__ convB,
                           float* __restrict__ out,
                           float* __restrict__ spart,  // [NSLOT][2*H]
                           int N) {
    __shared__ float red[4][256];  // 4 KB
    int tid = threadIdx.x;
    int wave = tid >> 6;
    int lane = tid & 63;
    int sub = lane >> 5;          // half-wave
    int hl = lane & 31;
    int stream = wave * 2 + sub;  // 0..7
    int c0 = hl * 8;              // gather channel base (8 channels/lane)
    const ushort* tp = (const ushort*)t;
    float sv = 0.f, sq = 0.f;
    int n0 = blockIdx.x * NB;
#pragma unroll 1
    for (int it = 0; it < NB; ++it) {
        int n = n0 + it;
        int s = rowstart[n], e = rowstart[n + 1];
        float a[8] = {};
#pragma unroll 1
        for (int j0 = s; j0 < e; j0 += 16) {
#pragma unroll
            for (int u = 0; u < 2; ++u) {
                int j = j0 + u * 8 + stream;
                int idx = n; float w = 0.f;
                if (j < e) { idx = csr_src[j]; w = csr_w[j]; }
                uint4 v = *(const uint4*)(tp + (size_t)idx * H + c0);
                a[0] += __uint_as_float(v.x << 16) * w;
                a[1] += __uint_as_float(v.x & 0xffff0000u) * w;
                a[2] += __uint_as_float(v.y << 16) * w;
                a[3] += __uint_as_float(v.y & 0xffff0000u) * w;
                a[4] += __uint_as_float(v.z << 16) * w;
                a[5] += __uint_as_float(v.z & 0xffff0000u) * w;
                a[6] += __uint_as_float(v.w << 16) * w;
                a[7] += __uint_as_float(v.w & 0xffff0000u) * w;
            }
        }
#pragma unroll
        for (int k = 0; k < 8; ++k) a[k] += __shfl_xor(a[k], 32);
        if (sub == 0) {
            *(float4*)&red[wave][c0] = make_float4(a[0], a[1], a[2], a[3]);
            *(float4*)&red[wave][c0 + 4] = make_float4(a[4], a[5], a[6], a[7]);
        }
        __syncthreads();
        int c = tid;  // channel
        float val = red[0][c] + red[1][c] + red[2][c] + red[3][c];
        float dn = dinv[n];
        val += __bfloat162float(t[(size_t)n * H + c]) * (dn * dn) + convB[c];
        out[(size_t)n * H + c] = val;
        sv += val; sq += val * val;
        __syncthreads();
    }
    float* sp = spart + (size_t)(blockIdx.x & (NSLOT - 1)) * (2 * H);
    atomicAdd(&sp[tid], sv);
    atomicAdd(&sp[H + tid], sq);
}

// ---------------- stats partials -> BN affine params sc/sh ----------------
__global__ void make_bnparams_kernel(const float* __restrict__ spart,
                                     const float* __restrict__ gamma,
                                     const float* __restrict__ beta,
                                     float* __restrict__ sc, float* __restrict__ sh) {
    int c = threadIdx.x;  // H
    float s = 0.f, s2 = 0.f;
#pragma unroll 8
    for (int i = 0; i < NSLOT; ++i) {
        s  += spart[(size_t)i * (2 * H) + c];
        s2 += spart[(size_t)i * (2 * H) + H + c];
    }
    float invN = 1.0f / (float)N_NODES;
    float mean = s * invN;
    float var = s2 * invN - mean * mean;
    float k = gamma[c] / sqrtf(var + EPS_BN);
    sc[c] = k;
    sh[c] = beta[c] - mean * k;
}

// ---------------- global mean pool (batch sorted), fused BN+ReLU on fp32 agg out ----
__global__ __launch_bounds__(256) void pool_kernel(const float* __restrict__ t2,
                            const int* __restrict__ batch,
                            const float* __restrict__ sc, const float* __restrict__ sh,
                            float* __restrict__ g, int N) {
    __shared__ float4 red[4][64];
    int gid = blockIdx.x;
    int lo = 0, hi = N;
    while (lo < hi) { int mid = (lo + hi) >> 1; if (batch[mid] < gid) lo = mid + 1; else hi = mid; }
    int s = lo;
    lo = s; hi = N;
    while (lo < hi) { int mid = (lo + hi) >> 1; if (batch[mid] < gid + 1) lo = mid + 1; else hi = mid; }
    int e = lo;
    int wave = threadIdx.x >> 6;
    int lane = threadIdx.x & 63;
    float4 scv = *(const float4*)(sc + lane * 4);
    float4 shv = *(const float4*)(sh + lane * 4);
    float a0 = 0.f, a1 = 0.f, a2 = 0.f, a3 = 0.f;
    for (int r = s + wave; r < e; r += 4) {
        float4 v = *(const float4*)(t2 + (size_t)r * H + lane * 4);
        // match old path: values were rounded to bf16 before pooling
        a0 += __bfloat162float(__float2bfloat16(fmaxf(v.x * scv.x + shv.x, 0.f)));
        a1 += __bfloat162float(__float2bfloat16(fmaxf(v.y * scv.y + shv.y, 0.f)));
        a2 += __bfloat162float(__float2bfloat16(fmaxf(v.z * scv.z + shv.z, 0.f)));
        a3 += __bfloat162float(__float2bfloat16(fmaxf(v.w * scv.w + shv.w, 0.f)));
    }
    red[wave][lane] = make_float4(a0, a1, a2, a3);
    __syncthreads();
    int c = threadIdx.x;
    const float* rf = (const float*)red;
    float sum = rf[c] + rf[256 + c] + rf[512 + c] + rf[768 + c];
    g[(size_t)gid * H + c] = sum / fmaxf((float)(e - s), 1.0f);
}

// ---------------- FC with compile-time K/NN ----------------
template <int K, int NN>
__global__ __launch_bounds__(256) void fc_lds_kernel(const float* __restrict__ in,
                                                     const float* __restrict__ W,
                                                     const float* __restrict__ b,
                                                     float* __restrict__ out) {
    __shared__ float row[K];
    int g = blockIdx.x;
    for (int k = threadIdx.x; k < K; k += 256) row[k] = in[(size_t)g * K + k];
    __syncthreads();
    int hc = threadIdx.x;
    if (hc < NN) {
        float acc = b[hc];
#pragma unroll
        for (int k = 0; k < K; ++k) acc += row[k] * W[k * NN + hc];
        out[(size_t)g * NN + hc] = acc;
    }
}

// ---------------- final FC ----------------
__global__ void fc_out_kernel(const float* __restrict__ in, const float* __restrict__ W,
                              const float* __restrict__ b, float* __restrict__ out) {
    int t = blockIdx.x * blockDim.x + threadIdx.x;
    if (t >= G_GRAPHS * C_OUT) return;
    int g = t / C_OUT, c = t % C_OUT;
    float acc = b[c];
#pragma unroll 16
    for (int k = 0; k < H; ++k) acc += in[(size_t)g * H + k] * W[k * C_OUT + c];
    out[t] = acc;
}

// ---------------- BN over small [G,H] ----------------
__global__ void bn_head_kernel(const float* __restrict__ in, const float* __restrict__ gamma,
                               const float* __restrict__ beta, float* __restrict__ out,
                               int Grows, int relu) {
    int c = blockIdx.x;
    int r = threadIdx.x;
    __shared__ float red[G_GRAPHS];
    float v = in[r * H + c];
    red[r] = v;
    __syncthreads();
    for (int off = G_GRAPHS / 2; off > 0; off >>= 1) {
        if (r < off) red[r] += red[r + off];
        __syncthreads();
    }
    float mean = red[0] / (float)Grows;
    __syncthreads();
    float d = v - mean;
    red[r] = d * d;
    __syncthreads();
    for (int off = G_GRAPHS / 2; off > 0; off >>= 1) {
        if (r < off) red[r] += red[r + off];
        __syncthreads();
    }
    float var = red[0] / (float)Grows;
    float y = gamma[c] * d / sqrtf(var + EPS_BN) + beta[c];
    if (relu) y = fmaxf(y, 0.f);
    out[r * H + c] = y;
}

extern "C" void kernel_launch(void* const* d_in, const int* in_sizes, int n_in,
                              void* d_out, int out_size, void* d_ws, size_t ws_size,
                              hipStream_t stream) {
    const float* x     = (const float*)d_in[0];
    const int*   edge  = (const int*)d_in[1];
    const int*   batch = (const int*)d_in[2];
    const float* encW  = (const float*)d_in[3];
    const float* encB  = (const float*)d_in[4];
    const float* convW = (const float*)d_in[5];
    const float* convB = (const float*)d_in[6];
    const float* bnG   = (const float*)d_in[7];
    const float* bnB   = (const float*)d_in[8];
    const float* fcW1  = (const float*)d_in[9];
    const float* fcB1  = (const float*)d_in[10];
    const float* fcG1  = (const float*)d_in[11];
    const float* fcBe1 = (const float*)d_in[12];
    const float* fcW2  = (const float*)d_in[13];
    const float* fcB2  = (const float*)d_in[14];
    const float* fcG2  = (const float*)d_in[15];
    const float* fcBe2 = (const float*)d_in[16];
    const float* fcW3  = (const float*)d_in[17];
    const float* fcB3  = (const float*)d_in[18];
    float* out = (float*)d_out;

    const int* srcIdx = edge;
    const int* dstIdx = edge + N_EDGES;

    char* base = (char*)d_ws;
    size_t off = 0;
    auto alloc = [&](size_t bytes) -> void* {
        void* p = base + off;
        off = (off + bytes + 255) & ~(size_t)255;
        return p;
    };
    int*   cnt      = (int*)alloc(N_NODES * 4);
    int*   cursor   = (int*)alloc(N_NODES * 4);
    int*   rowstart = (int*)alloc((N_NODES + 1) * 4);
    float* dinv     = (float*)alloc(N_NODES * 4);
    int*   csr_src  = (int*)alloc(N_EDGES * 4);
    float* csr_w    = (float*)alloc(N_EDGES * 4);
    float* spart    = (float*)alloc((size_t)LAYERS * NSLOT * 2 * H * 4);
    float* scbuf    = (float*)alloc((size_t)LAYERS * H * 4);
    float* shbuf    = (float*)alloc((size_t)LAYERS * H * 4);
    __hip_bfloat16* xbf    = (__hip_bfloat16*)alloc((size_t)N_NODES * XDIM * 2);
    __hip_bfloat16* encWT  = (__hip_bfloat16*)alloc((size_t)H * XDIM * 2);
    __hip_bfloat16* convWT = (__hip_bfloat16*)alloc((size_t)LAYERS * H * H * 2);
    __hip_bfloat16* hbf    = (__hip_bfloat16*)alloc((size_t)N_NODES * H * 2);
    __hip_bfloat16* tbf    = (__hip_bfloat16*)alloc((size_t)N_NODES * H * 2);
    float* t2buf = (float*)alloc((size_t)N_NODES * H * 4);
    float* gpool = (float*)alloc(G_GRAPHS * H * 4);
    float* m1    = (float*)alloc(G_GRAPHS * H * 4);
    float* m2    = (float*)alloc(G_GRAPHS * H * 4);

    // cnt+cursor are contiguous in ws -> one memset
    hipMemsetAsync(cnt, 0, (size_t)((char*)rowstart - (char*)cnt), stream);
    hipMemsetAsync(spart, 0, (size_t)LAYERS * NSLOT * 2 * H * 4, stream);

    // CSR build
    hist_kernel<<<(N_EDGES + 255) / 256, 256, 0, stream>>>(dstIdx, cnt, N_EDGES);
    scan_kernel<<<1, 1024, 0, stream>>>(cnt, rowstart, dinv, N_NODES);
    fill_kernel<<<(N_EDGES + 255) / 256, 256, 0, stream>>>(srcIdx, dstIdx, rowstart, cursor,
                                                           dinv, csr_src, csr_w, N_EDGES);

    // casts
    cast_bf16_kernel<<<(N_NODES * XDIM + 255) / 256, 256, 0, stream>>>(x, xbf, N_NODES * XDIM);
    tcast_kernel<<<(XDIM * H + 255) / 256, 256, 0, stream>>>(encW, encWT, XDIM, H, 1);
    tcast_kernel<<<(LAYERS * H * H + 255) / 256, 256, 0, stream>>>(convW, convWT, H, H, LAYERS);

    // encoder: h = x @ encW + encB
    dim3 gridG((N_NODES + 63) / 64, H / 128);
    gemm_bf16_kernel<XDIM, false><<<gridG, 256, 0, stream>>>(
        xbf, encWT, encB, nullptr, nullptr, hbf, N_NODES, H);

    // conv layers: gemm (BN fused into A-staging for l>=1), agg(+stats), bnparams
    for (int l = 0; l < LAYERS; ++l) {
        float* spartL = spart + (size_t)l * NSLOT * 2 * H;
        if (l == 0) {
            gemm_bf16_kernel<H, false><<<gridG, 256, 0, stream>>>(
                hbf, convWT + (size_t)l * H * H, nullptr, nullptr, nullptr, tbf, N_NODES, H);
        } else {
            gemm_bf16_kernel<H, true><<<gridG, 256, 0, stream>>>(
                t2buf, convWT + (size_t)l * H * H, nullptr,
                scbuf + (size_t)(l - 1) * H, shbuf + (size_t)(l - 1) * H, tbf, N_NODES, H);
        }
        agg_kernel<<<N_NODES / NB, 256, 0, stream>>>(tbf, rowstart, csr_src, csr_w, dinv,
                                                     convB + l * H, t2buf, spartL, N_NODES);
        make_bnparams_kernel<<<1, H, 0, stream>>>(spartL, bnG + l * H, bnB + l * H,
                                                  scbuf + (size_t)l * H, shbuf + (size_t)l * H);
    }

    // pool (BN+ReLU of layer 3 fused)
    pool_kernel<<<G_GRAPHS, 256, 0, stream>>>(t2buf, batch,
                                              scbuf + (size_t)(LAYERS - 1) * H,
                                              shbuf + (size_t)(LAYERS - 1) * H, gpool, N_NODES);

    // head
    fc_lds_kernel<H, H><<<G_GRAPHS, 256, 0, stream>>>(gpool, fcW1, fcB1, m1);
    bn_head_kernel<<<H, G_GRAPHS, 0, stream>>>(m1, fcG1, fcBe1, m1, G_GRAPHS, 1);
    fc_lds_kernel<H, H><<<G_GRAPHS, 256, 0, stream>>>(m1, fcW2, fcB2, m2);
    bn_head_kernel<<<H, G_GRAPHS, 0, stream>>>(m2, fcG2, fcBe2, m2, G_GRAPHS, 0);
    fc_out_kernel<<<(G_GRAPHS * C_OUT + 255) / 256, 256, 0, stream>>>(m2, fcW3, fcB3, out);
}

// Round 9
// 446.647 us; speedup vs baseline: 1.2568x; 1.0152x over previous
//
#include <hip/hip_runtime.h>
#include <hip/hip_bf16.h>
#include <cstddef>

#define N_NODES 20000
#define N_EDGES 320000
#define XDIM 128
#define H 256
#define LAYERS 4
#define G_GRAPHS 128
#define C_OUT 10
#define EPS_BN 1e-5f
#define NSLOT 64          // stats partial slots
#define NB 8              // nodes per block in agg

typedef __attribute__((ext_vector_type(8))) short short8;
typedef __attribute__((ext_vector_type(4))) float f32x4;
typedef __attribute__((address_space(3))) unsigned int lds_u32;
typedef const __attribute__((address_space(1))) unsigned int glob_u32;

// ---------------- degree histogram (by dst) ----------------
__global__ void hist_kernel(const int* __restrict__ dst, int* __restrict__ cnt, int E) {
    int e = blockIdx.x * blockDim.x + threadIdx.x;
    if (e < E) atomicAdd(&cnt[dst[e]], 1);
}

// ---------------- exclusive scan of cnt -> rowstart[N+1], fused dinv ----------------
__global__ void scan_kernel(const int* __restrict__ cnt, int* __restrict__ rowstart,
                            float* __restrict__ dinv, int N) {
    __shared__ int partial[1024];
    int tid = threadIdx.x;
    int chunk = (N + 1023) / 1024;
    int start = tid * chunk;
    int lsum = 0;
    for (int i = 0; i < chunk; ++i) {
        int idx = start + i;
        if (idx < N) {
            int c = cnt[idx];
            dinv[idx] = 1.0f / sqrtf((float)c + 1.0f);
            lsum += c;
        }
    }
    partial[tid] = lsum;
    __syncthreads();
    for (int off = 1; off < 1024; off <<= 1) {
        int v = (tid >= off) ? partial[tid - off] : 0;
        __syncthreads();
        partial[tid] += v;
        __syncthreads();
    }
    int run = (tid == 0) ? 0 : partial[tid - 1];
    for (int i = 0; i < chunk; ++i) {
        int idx = start + i;
        if (idx < N) { rowstart[idx] = run; run += cnt[idx]; }
    }
    if (tid == 1023) rowstart[N] = partial[1023];
}

// ---------------- CSR fill ----------------
__global__ void fill_kernel(const int* __restrict__ src, const int* __restrict__ dst,
                            const int* __restrict__ rowstart, int* __restrict__ cursor,
                            const float* __restrict__ dinv,
                            int* __restrict__ csr_src, float* __restrict__ csr_w, int E) {
    int e = blockIdx.x * blockDim.x + threadIdx.x;
    if (e < E) {
        int s = src[e], d = dst[e];
        int pos = rowstart[d] + atomicAdd(&cursor[d], 1);
        csr_src[pos] = s;
        csr_w[pos] = dinv[s] * dinv[d];
    }
}

// ---------------- fused prep: cast x -> bf16, transpose+cast encW & convW ----------------
__global__ void prep_kernel(const float* __restrict__ x, const float* __restrict__ encW,
                            const float* __restrict__ convW,
                            __hip_bfloat16* __restrict__ xbf,
                            __hip_bfloat16* __restrict__ encWT,
                            __hip_bfloat16* __restrict__ convWT) {
    int i = blockIdx.x * blockDim.x + threadIdx.x;
    const int nx = N_NODES * XDIM;
    const int ne = XDIM * H;
    const int nc = LAYERS * H * H;
    if (i < nx) {
        xbf[i] = __float2bfloat16(x[i]);
    } else if (i < nx + ne) {
        int j = i - nx;
        int r = j / H, c = j - r * H;
        encWT[c * XDIM + r] = __float2bfloat16(encW[j]);
    } else if (i < nx + ne + nc) {
        int j = i - nx - ne;
        int l = j / (H * H), rem = j - l * (H * H);
        int r = rem / H, c = rem - r * H;
        convWT[(size_t)l * H * H + c * H + r] = __float2bfloat16(convW[j]);
    }
}

__device__ __forceinline__ short bf16bits(float x) {
    __hip_bfloat16 b = __float2bfloat16(x);
    return *(short*)&b;
}

// ---------------- bf16 MFMA GEMM, double-buffered LDS (one barrier/iter) -----------
// 64x128 tile, 4 waves of 32x64, 16x16x32. B (and A when plain bf16) staged via
// async global_load_lds 16B. When FUSE_BN: A is the fp32 agg output; BN params
// are computed per-block from spart (bit-identical to the old make_bnparams),
// BN+ReLU applied while staging A (load->regs prefetch, convert+ds_write after
// the barrier so the global loads overlap compute of the previous K-slice).
template <int K, bool FUSE_BN>
__global__ __launch_bounds__(256) void gemm_bf16_kernel(
    const void* __restrict__ Ain,           // [M,K] bf16 (plain) or fp32 (FUSE_BN)
    const __hip_bfloat16* __restrict__ BT,  // [Nn,K] row-major (B transposed)
    const float* __restrict__ bias,         // [Nn] or nullptr
    const float* __restrict__ spart,        // [NSLOT][2H] stats partials (FUSE_BN)
    const float* __restrict__ gamma,        // [H] (FUSE_BN)
    const float* __restrict__ beta,         // [H] (FUSE_BN)
    __hip_bfloat16* __restrict__ Cbf,       // [M,Nn]
    int M, int Nn) {
    __shared__ short As[2][64 * 32];    // 8 KB
    __shared__ short Bs[2][128 * 32];   // 16 KB
    __shared__ float scs[H];
    __shared__ float shs[H];
    const short* Ash = (const short*)Ain;
    const float* Af = (const float*)Ain;
    const short* Bsh = (const short*)BT;
    int tid = threadIdx.x;
    int lane = tid & 63;
    int wave = tid >> 6;
    int quad = lane >> 4;
    int lr = lane & 15;
    int wm = (wave & 1) * 32;
    int wn = (wave >> 1) * 64;
    int Mblk = blockIdx.x * 64;
    int Nblk = blockIdx.y * 128;

    f32x4 acc[2][4];
#pragma unroll
    for (int i = 0; i < 2; ++i)
#pragma unroll
        for (int j = 0; j < 4; ++j) acc[i][j] = (f32x4){0.f, 0.f, 0.f, 0.f};

    // staging slots (constant over K)
    int srow = tid >> 2, sqs = tid & 3;
    int sqg = sqs ^ ((srow >> 1) & 3);
    int arow = Mblk + srow; if (arow >= M) arow = M - 1;
    int s1 = 256 + tid;
    int brow0 = Nblk + (tid >> 2);
    int qg0 = sqg;
    int brow1 = Nblk + (s1 >> 2);
    int qg1 = (s1 & 3) ^ (((s1 >> 2) >> 1) & 3);

    if (FUSE_BN) {
        // per-block BN params (identical arithmetic to old make_bnparams)
        int c = tid;
        float s = 0.f, s2 = 0.f;
#pragma unroll 8
        for (int i = 0; i < NSLOT; ++i) {
            s  += spart[(size_t)i * (2 * H) + c];
            s2 += spart[(size_t)i * (2 * H) + H + c];
        }
        float invN = 1.0f / (float)N_NODES;
        float mean = s * invN;
        float var = s2 * invN - mean * mean;
        float kk = gamma[c] / sqrtf(var + EPS_BN);
        scs[c] = kk;
        shs[c] = beta[c] - mean * kk;
        __syncthreads();
    }

    float4 ra0, ra1;  // FUSE_BN A prefetch regs
    auto loadA_f = [&](int k0) {
        int kc = k0 + sqg * 8;
        ra0 = *(const float4*)(Af + (size_t)arow * K + kc);
        ra1 = *(const float4*)(Af + (size_t)arow * K + kc + 4);
    };
    auto storeA_f = [&](int buf, int k0) {
        int kc = k0 + sqg * 8;
        float4 c0 = *(const float4*)&scs[kc];
        float4 c1 = *(const float4*)&scs[kc + 4];
        float4 h0 = *(const float4*)&shs[kc];
        float4 h1 = *(const float4*)&shs[kc + 4];
        short8 pk;
        pk[0] = bf16bits(fmaxf(ra0.x * c0.x + h0.x, 0.f));
        pk[1] = bf16bits(fmaxf(ra0.y * c0.y + h0.y, 0.f));
        pk[2] = bf16bits(fmaxf(ra0.z * c0.z + h0.z, 0.f));
        pk[3] = bf16bits(fmaxf(ra0.w * c0.w + h0.w, 0.f));
        pk[4] = bf16bits(fmaxf(ra1.x * c1.x + h1.x, 0.f));
        pk[5] = bf16bits(fmaxf(ra1.y * c1.y + h1.y, 0.f));
        pk[6] = bf16bits(fmaxf(ra1.z * c1.z + h1.z, 0.f));
        pk[7] = bf16bits(fmaxf(ra1.w * c1.w + h1.w, 0.f));
        *(short8*)&As[buf][srow * 32 + sqs * 8] = pk;
    };
    auto stageA_async = [&](int buf, int k0) {
        __builtin_amdgcn_global_load_lds((glob_u32*)(Ash + (size_t)arow * K + k0 + sqg * 8),
                                         (lds_u32*)&As[buf][0] + wave * 256, 16, 0, 0);
    };
    auto stageB = [&](int buf, int k0) {
        __builtin_amdgcn_global_load_lds((glob_u32*)(Bsh + (size_t)brow0 * K + k0 + qg0 * 8),
                                         (lds_u32*)&Bs[buf][0] + wave * 256, 16, 0, 0);
        __builtin_amdgcn_global_load_lds((glob_u32*)(Bsh + (size_t)brow1 * K + k0 + qg1 * 8),
                                         (lds_u32*)&Bs[buf][0] + 1024 + wave * 256, 16, 0, 0);
    };

    constexpr int NK = K / 32;
    if (FUSE_BN) loadA_f(0); else stageA_async(0, 0);
    stageB(0, 0);
#pragma unroll
    for (int k = 0; k < NK; ++k) {
        int buf = k & 1;
        if (FUSE_BN) storeA_f(buf, k * 32);
        __syncthreads();   // buf-k staging complete (vmcnt + lgkm drained by all waves)
        if (k + 1 < NK) {
            if (FUSE_BN) loadA_f((k + 1) * 32); else stageA_async(buf ^ 1, (k + 1) * 32);
            stageB(buf ^ 1, (k + 1) * 32);
        }
        short8 af[2], bfr[4];
#pragma unroll
        for (int mi = 0; mi < 2; ++mi) {
            int r = wm + mi * 16 + lr;
            af[mi] = *(const short8*)&As[buf][r * 32 + (quad ^ ((r >> 1) & 3)) * 8];
        }
#pragma unroll
        for (int ni = 0; ni < 4; ++ni) {
            int r = wn + ni * 16 + lr;
            bfr[ni] = *(const short8*)&Bs[buf][r * 32 + (quad ^ ((r >> 1) & 3)) * 8];
        }
#pragma unroll
        for (int mi = 0; mi < 2; ++mi)
#pragma unroll
            for (int ni = 0; ni < 4; ++ni)
                acc[mi][ni] = __builtin_amdgcn_mfma_f32_16x16x32_bf16(af[mi], bfr[ni], acc[mi][ni], 0, 0, 0);
    }
#pragma unroll
    for (int mi = 0; mi < 2; ++mi) {
#pragma unroll
        for (int r = 0; r < 4; ++r) {
            int m = Mblk + wm + mi * 16 + quad * 4 + r;
            if (m < M) {
#pragma unroll
                for (int ni = 0; ni < 4; ++ni) {
                    int n = Nblk + wn + ni * 16 + lr;
                    float v = acc[mi][ni][r];
                    if (bias) v += bias[n];
                    Cbf[(size_t)m * Nn + n] = __float2bfloat16(v);
                }
            }
        }
    }
}

// ---------------- aggregation + fused BN-stats (R7 structure, unchanged) ----------
__global__ __launch_bounds__(256) void agg_kernel(const __hip_bfloat16* __restrict__ t,
                           const int* __restrict__ rowstart,
                           const int* __restrict__ csr_src,
                           const float* __restrict__ csr_w,
                           const float* __restrict__ dinv,
                           const float* __restrict__ convB,
                           float* __restrict__ out,
                           float* __restrict__ spart,  // [NSLOT][2*H]
                           int N) {
    __shared__ float red[4][256];  // 4 KB
    int tid = threadIdx.x;
    int wave = tid >> 6;
    int lane = tid & 63;
    int sub = lane >> 5;          // half-wave
    int hl = lane & 31;
    int stream = wave * 2 + sub;  // 0..7
    int c0 = hl * 8;              // gather channel base (8 channels/lane)
    const ushort* tp = (const ushort*)t;
    float sv = 0.f, sq = 0.f;
    int n0 = blockIdx.x * NB;
#pragma unroll 1
    for (int it = 0; it < NB; ++it) {
        int n = n0 + it;
        int s = rowstart[n], e = rowstart[n + 1];
        float a[8] = {};
#pragma unroll 1
        for (int j0 = s; j0 < e; j0 += 16) {
#pragma unroll
            for (int u = 0; u < 2; ++u) {
                int j = j0 + u * 8 + stream;
                int idx = n; float w = 0.f;
                if (j < e) { idx = csr_src[j]; w = csr_w[j]; }
                uint4 v = *(const uint4*)(tp + (size_t)idx * H + c0);
                a[0] += __uint_as_float(v.x << 16) * w;
                a[1] += __uint_as_float(v.x & 0xffff0000u) * w;
                a[2] += __uint_as_float(v.y << 16) * w;
                a[3] += __uint_as_float(v.y & 0xffff0000u) * w;
                a[4] += __uint_as_float(v.z << 16) * w;
                a[5] += __uint_as_float(v.z & 0xffff0000u) * w;
                a[6] += __uint_as_float(v.w << 16) * w;
                a[7] += __uint_as_float(v.w & 0xffff0000u) * w;
            }
        }
#pragma unroll
        for (int k = 0; k < 8; ++k) a[k] += __shfl_xor(a[k], 32);
        if (sub == 0) {
            *(float4*)&red[wave][c0] = make_float4(a[0], a[1], a[2], a[3]);
            *(float4*)&red[wave][c0 + 4] = make_float4(a[4], a[5], a[6], a[7]);
        }
        __syncthreads();
        int c = tid;  // channel
        float val = red[0][c] + red[1][c] + red[2][c] + red[3][c];
        float dn = dinv[n];
        val += __bfloat162float(t[(size_t)n * H + c]) * (dn * dn) + convB[c];
        out[(size_t)n * H + c] = val;
        sv += val; sq += val * val;
        __syncthreads();
    }
    float* sp = spart + (size_t)(blockIdx.x & (NSLOT - 1)) * (2 * H);
    atomicAdd(&sp[tid], sv);
    atomicAdd(&sp[H + tid], sq);
}

// ---------------- global mean pool, fused per-block BN params + BN+ReLU ----------
__global__ __launch_bounds__(256) void pool_kernel(const float* __restrict__ t2,
                            const int* __restrict__ batch,
                            const float* __restrict__ spart,
                            const float* __restrict__ gamma,
                            const float* __restrict__ beta,
                            float* __restrict__ g, int N) {
    __shared__ float4 red[4][64];
    __shared__ float scs[H];
    __shared__ float shs[H];
    {
        int c = threadIdx.x;
        float s = 0.f, s2 = 0.f;
#pragma unroll 8
        for (int i = 0; i < NSLOT; ++i) {
            s  += spart[(size_t)i * (2 * H) + c];
            s2 += spart[(size_t)i * (2 * H) + H + c];
        }
        float invN = 1.0f / (float)N_NODES;
        float mean = s * invN;
        float var = s2 * invN - mean * mean;
        float kk = gamma[c] / sqrtf(var + EPS_BN);
        scs[c] = kk;
        shs[c] = beta[c] - mean * kk;
    }
    __syncthreads();
    int gid = blockIdx.x;
    int lo = 0, hi = N;
    while (lo < hi) { int mid = (lo + hi) >> 1; if (batch[mid] < gid) lo = mid + 1; else hi = mid; }
    int s = lo;
    lo = s; hi = N;
    while (lo < hi) { int mid = (lo + hi) >> 1; if (batch[mid] < gid + 1) lo = mid + 1; else hi = mid; }
    int e = lo;
    int wave = threadIdx.x >> 6;
    int lane = threadIdx.x & 63;
    float4 scv = *(const float4*)&scs[lane * 4];
    float4 shv = *(const float4*)&shs[lane * 4];
    float a0 = 0.f, a1 = 0.f, a2 = 0.f, a3 = 0.f;
    for (int r = s + wave; r < e; r += 4) {
        float4 v = *(const float4*)(t2 + (size_t)r * H + lane * 4);
        a0 += __bfloat162float(__float2bfloat16(fmaxf(v.x * scv.x + shv.x, 0.f)));
        a1 += __bfloat162float(__float2bfloat16(fmaxf(v.y * scv.y + shv.y, 0.f)));
        a2 += __bfloat162float(__float2bfloat16(fmaxf(v.z * scv.z + shv.z, 0.f)));
        a3 += __bfloat162float(__float2bfloat16(fmaxf(v.w * scv.w + shv.w, 0.f)));
    }
    red[wave][lane] = make_float4(a0, a1, a2, a3);
    __syncthreads();
    int c = threadIdx.x;
    const float* rf = (const float*)red;
    float sum = rf[c] + rf[256 + c] + rf[512 + c] + rf[768 + c];
    g[(size_t)gid * H + c] = sum / fmaxf((float)(e - s), 1.0f);
}

// ---------------- FC with compile-time K/NN ----------------
template <int K, int NN>
__global__ __launch_bounds__(256) void fc_lds_kernel(const float* __restrict__ in,
                                                     const float* __restrict__ W,
                                                     const float* __restrict__ b,
                                                     float* __restrict__ out) {
    __shared__ float row[K];
    int g = blockIdx.x;
    for (int k = threadIdx.x; k < K; k += 256) row[k] = in[(size_t)g * K + k];
    __syncthreads();
    int hc = threadIdx.x;
    if (hc < NN) {
        float acc = b[hc];
#pragma unroll
        for (int k = 0; k < K; ++k) acc += row[k] * W[k * NN + hc];
        out[(size_t)g * NN + hc] = acc;
    }
}

// ---------------- final FC ----------------
__global__ void fc_out_kernel(const float* __restrict__ in, const float* __restrict__ W,
                              const float* __restrict__ b, float* __restrict__ out) {
    int t = blockIdx.x * blockDim.x + threadIdx.x;
    if (t >= G_GRAPHS * C_OUT) return;
    int g = t / C_OUT, c = t % C_OUT;
    float acc = b[c];
#pragma unroll 16
    for (int k = 0; k < H; ++k) acc += in[(size_t)g * H + k] * W[k * C_OUT + c];
    out[t] = acc;
}

// ---------------- BN over small [G,H] ----------------
__global__ void bn_head_kernel(const float* __restrict__ in, const float* __restrict__ gamma,
                               const float* __restrict__ beta, float* __restrict__ out,
                               int Grows, int relu) {
    int c = blockIdx.x;
    int r = threadIdx.x;
    __shared__ float red[G_GRAPHS];
    float v = in[r * H + c];
    red[r] = v;
    __syncthreads();
    for (int off = G_GRAPHS / 2; off > 0; off >>= 1) {
        if (r < off) red[r] += red[r + off];
        __syncthreads();
    }
    float mean = red[0] / (float)Grows;
    __syncthreads();
    float d = v - mean;
    red[r] = d * d;
    __syncthreads();
    for (int off = G_GRAPHS / 2; off > 0; off >>= 1) {
        if (r < off) red[r] += red[r + off];
        __syncthreads();
    }
    float var = red[0] / (float)Grows;
    float y = gamma[c] * d / sqrtf(var + EPS_BN) + beta[c];
    if (relu) y = fmaxf(y, 0.f);
    out[r * H + c] = y;
}

extern "C" void kernel_launch(void* const* d_in, const int* in_sizes, int n_in,
                              void* d_out, int out_size, void* d_ws, size_t ws_size,
                              hipStream_t stream) {
    const float* x     = (const float*)d_in[0];
    const int*   edge  = (const int*)d_in[1];
    const int*   batch = (const int*)d_in[2];
    const float* encW  = (const float*)d_in[3];
    const float* encB  = (const float*)d_in[4];
    const float* convW = (const float*)d_in[5];
    const float* convB = (const float*)d_in[6];
    const float* bnG   = (const float*)d_in[7];
    const float* bnB   = (const float*)d_in[8];
    const float* fcW1  = (const float*)d_in[9];
    const float* fcB1  = (const float*)d_in[10];
    const float* fcG1  = (const float*)d_in[11];
    const float* fcBe1 = (const float*)d_in[12];
    const float* fcW2  = (const float*)d_in[13];
    const float* fcB2  = (const float*)d_in[14];
    const float* fcG2  = (const float*)d_in[15];
    const float* fcBe2 = (const float*)d_in[16];
    const float* fcW3  = (const float*)d_in[17];
    const float* fcB3  = (const float*)d_in[18];
    float* out = (float*)d_out;

    const int* srcIdx = edge;
    const int* dstIdx = edge + N_EDGES;

    char* base = (char*)d_ws;
    size_t off = 0;
    auto alloc = [&](size_t bytes) -> void* {
        void* p = base + off;
        off = (off + bytes + 255) & ~(size_t)255;
        return p;
    };
    int*   cnt      = (int*)alloc(N_NODES * 4);
    int*   cursor   = (int*)alloc(N_NODES * 4);
    int*   rowstart = (int*)alloc((N_NODES + 1) * 4);
    float* dinv     = (float*)alloc(N_NODES * 4);
    int*   csr_src  = (int*)alloc(N_EDGES * 4);
    float* csr_w    = (float*)alloc(N_EDGES * 4);
    float* spart    = (float*)alloc((size_t)LAYERS * NSLOT * 2 * H * 4);
    __hip_bfloat16* xbf    = (__hip_bfloat16*)alloc((size_t)N_NODES * XDIM * 2);
    __hip_bfloat16* encWT  = (__hip_bfloat16*)alloc((size_t)H * XDIM * 2);
    __hip_bfloat16* convWT = (__hip_bfloat16*)alloc((size_t)LAYERS * H * H * 2);
    __hip_bfloat16* hbf    = (__hip_bfloat16*)alloc((size_t)N_NODES * H * 2);
    __hip_bfloat16* tbf    = (__hip_bfloat16*)alloc((size_t)N_NODES * H * 2);
    float* t2buf = (float*)alloc((size_t)N_NODES * H * 4);
    float* gpool = (float*)alloc(G_GRAPHS * H * 4);
    float* m1    = (float*)alloc(G_GRAPHS * H * 4);
    float* m2    = (float*)alloc(G_GRAPHS * H * 4);

    // cnt+cursor are contiguous in ws -> one memset
    hipMemsetAsync(cnt, 0, (size_t)((char*)rowstart - (char*)cnt), stream);
    hipMemsetAsync(spart, 0, (size_t)LAYERS * NSLOT * 2 * H * 4, stream);

    // CSR build
    hist_kernel<<<(N_EDGES + 255) / 256, 256, 0, stream>>>(dstIdx, cnt, N_EDGES);
    scan_kernel<<<1, 1024, 0, stream>>>(cnt, rowstart, dinv, N_NODES);
    fill_kernel<<<(N_EDGES + 255) / 256, 256, 0, stream>>>(srcIdx, dstIdx, rowstart, cursor,
                                                           dinv, csr_src, csr_w, N_EDGES);

    // fused prep (cast + transposes)
    {
        int total = N_NODES * XDIM + XDIM * H + LAYERS * H * H;
        prep_kernel<<<(total + 255) / 256, 256, 0, stream>>>(x, encW, convW, xbf, encWT, convWT);
    }

    // encoder: h = x @ encW + encB
    dim3 gridG((N_NODES + 63) / 64, H / 128);
    gemm_bf16_kernel<XDIM, false><<<gridG, 256, 0, stream>>>(
        xbf, encWT, encB, nullptr, nullptr, nullptr, hbf, N_NODES, H);

    // conv layers: gemm (BN of prev layer fused into A-staging for l>=1), agg(+stats)
    for (int l = 0; l < LAYERS; ++l) {
        float* spartL = spart + (size_t)l * NSLOT * 2 * H;
        if (l == 0) {
            gemm_bf16_kernel<H, false><<<gridG, 256, 0, stream>>>(
                hbf, convWT + (size_t)l * H * H, nullptr, nullptr, nullptr, nullptr,
                tbf, N_NODES, H);
        } else {
            float* spartP = spart + (size_t)(l - 1) * NSLOT * 2 * H;
            gemm_bf16_kernel<H, true><<<gridG, 256, 0, stream>>>(
                t2buf, convWT + (size_t)l * H * H, nullptr,
                spartP, bnG + (size_t)(l - 1) * H, bnB + (size_t)(l - 1) * H,
                tbf, N_NODES, H);
        }
        agg_kernel<<<N_NODES / NB, 256, 0, stream>>>(tbf, rowstart, csr_src, csr_w, dinv,
                                                     convB + l * H, t2buf, spartL, N_NODES);
    }

    // pool (BN+ReLU of layer 3 fused, params computed per-block)
    pool_kernel<<<G_GRAPHS, 256, 0, stream>>>(
        t2buf, batch, spart + (size_t)(LAYERS - 1) * NSLOT * 2 * H,
        bnG + (size_t)(LAYERS - 1) * H, bnB + (size_t)(LAYERS - 1) * H, gpool, N_NODES);

    // head
    fc_lds_kernel<H, H><<<G_GRAPHS, 256, 0, stream>>>(gpool, fcW1, fcB1, m1);
    bn_head_kernel<<<H, G_GRAPHS, 0, stream>>>(m1, fcG1, fcBe1, m1, G_GRAPHS, 1);
    fc_lds_kernel<H, H><<<G_GRAPHS, 256, 0, stream>>>(m1, fcW2, fcB2, m2);
    bn_head_kernel<<<H, G_GRAPHS, 0, stream>>>(m2, fcG2, fcBe2, m2, G_GRAPHS, 0);
    fc_out_kernel<<<(G_GRAPHS * C_OUT + 255) / 256, 256, 0, stream>>>(m2, fcW3, fcB3, out);
}